// Round 1
// 232.334 us; speedup vs baseline: 1.0575x; 1.0575x over previous
//
#include <hip/hip_runtime.h>
#include <math.h>
#include <string.h>

typedef __attribute__((ext_vector_type(8))) short bf16x8;
typedef __attribute__((ext_vector_type(4))) float f32x4;

namespace {
constexpr int TOUT = 32;            // output tile side
constexpr int IMG  = 512;
constexpr int HALO = 15;
constexpr int OUTW = IMG - HALO;    // 497
constexpr int NBLK = 16 * 16 * 96;  // 24576 blocks

struct WinPk { unsigned w[8]; };    // 16 bf16 Gaussian weights, packed pairs

// pack two pre-rounded (+0x8000) float bit patterns into [hi.bf16 : lo.bf16]
__device__ __forceinline__ unsigned prm(unsigned hi, unsigned lo) {
    return __builtin_amdgcn_perm(hi, lo, 0x07060302u);
}
}

// One block = one 32x32 output tile of one (batch,channel) plane.
// MFMA formulation: 16-tap conv = GEMM vs constant banded matrix
// W[k][n] = g[k-n]. One per-lane banded fragment wf[j] = g[(q*8+j)-(lane&15)]
// serves as B-operand (horizontal) and A-operand (vertical) of
// mfma_f32_16x16x32_bf16.
//
// LDS OVERLAY (v2): the H-phase output buffer HB[sig][outcol<32][hbrow<48]
// aliases rows 0..31 of S[sig][48][48] (element HB[s][oc][hr] == S[s][oc][hr]).
// Safety: in phase H, wave w touches ONLY plane w. It reads its 4 row-0..31
// A-fragments BEFORE issuing any HB write (same-wave DS ops execute in
// order), and the row-32..47 fragments are never overwritten (HB rows < 32).
// This cuts block LDS 31.2 KB -> 18.6 KB: occupancy cap 5 -> 8 blocks/CU.
//
// Phase A (v2): 288 items x 8 cols, all 256 threads (threads 0..31 take two
//   items). Per item: 2x float4 loads per image, bf16 round (+0x8000 trunc,
//   identical numerics to v1), q=a^2+b^2 / x=ab from the ROUNDED values,
//   one uint4 (b128) LDS write per plane -- bank-uniform, replacing v1's
//   4-way-conflicted 24x b32 writes. Row 47 / col 47 zero-padded (read with
//   zero weight; must be finite). MSE on owned 32x32 in fp32.
// Phase H: wave w = signal w: 6 MFMA tiles; C[row][outcol] -> bf16 pack ->
//   HB[sig][outcol][row] (b64 store).
// Phase V: wave w = output quadrant: per signal one MFMA, SSIM rational map,
//   masked sum. Tail: per-block double2 partial + reduce_kernel.
template <bool TWO_STAGE>
__global__ __launch_bounds__(256, 8)
void ssim_mse_kernel(const float* __restrict__ img1,
                     const float* __restrict__ img2,
                     WinPk wpk,
                     double2* __restrict__ partial,
                     double*  __restrict__ accum)
{
    __shared__ unsigned short S[4][48][48];   // 18,432 B; rows 0..31 double as HB
    __shared__ unsigned short gt[64];         // banded-weight lookup
    __shared__ float red[2][4];

    const int tid = threadIdx.x;
    const int ox0 = blockIdx.x * TOUT;
    const int oy0 = blockIdx.y * TOUT;
    const size_t plane_off = (size_t)blockIdx.z * (IMG * IMG);
    const float* __restrict__ p1 = img1 + plane_off;
    const float* __restrict__ p2 = img2 + plane_off;

    float mse_local = 0.0f, ssim_local = 0.0f;

    // ---- weight table: gt[i] = bf16 g[i-16] for i in [16,32), else 0 ----
    if (tid < 16) gt[tid] = 0;
    else if (tid >= 32 && tid < 64) gt[tid] = 0;
    else if (tid == 16) {
        #pragma unroll
        for (int k = 0; k < 8; ++k)
            *(unsigned*)&gt[16 + 2 * k] = wpk.w[k];
    }

    // ---------------- Phase A: stage signals + MSE ----------------
    // 288 items = 48 rows x 6 eight-col segments; item -> (r = it/6, cs8)
    for (int it = tid; it < 288; it += 256) {
        const int r   = (int)((unsigned)it / 6u);
        const int cs8 = it - 6 * r;
        const int c0  = 8 * cs8;
        if (r == 47) {                  // zero pad row
            const uint4 z = make_uint4(0u, 0u, 0u, 0u);
            *(uint4*)&S[0][47][c0] = z;
            *(uint4*)&S[1][47][c0] = z;
            *(uint4*)&S[2][47][c0] = z;
            *(uint4*)&S[3][47][c0] = z;
        } else {
            const int gy  = oy0 + r;
            const int gyc = gy < IMG ? gy : IMG - 1;
            const float* __restrict__ pa = p1 + (size_t)gyc * IMG;
            const float* __restrict__ pb = p2 + (size_t)gyc * IMG;
            float Af[8], Bf[8];
            if (ox0 + c0 + 8 <= IMG) {
                const float4 va0 = *(const float4*)(pa + ox0 + c0);
                const float4 va1 = *(const float4*)(pa + ox0 + c0 + 4);
                const float4 vb0 = *(const float4*)(pb + ox0 + c0);
                const float4 vb1 = *(const float4*)(pb + ox0 + c0 + 4);
                Af[0] = va0.x; Af[1] = va0.y; Af[2] = va0.z; Af[3] = va0.w;
                Af[4] = va1.x; Af[5] = va1.y; Af[6] = va1.z; Af[7] = va1.w;
                Bf[0] = vb0.x; Bf[1] = vb0.y; Bf[2] = vb0.z; Bf[3] = vb0.w;
                Bf[4] = vb1.x; Bf[5] = vb1.y; Bf[6] = vb1.z; Bf[7] = vb1.w;
            } else {
                #pragma unroll
                for (int j = 0; j < 8; ++j) {
                    int gx = ox0 + c0 + j; gx = gx < IMG ? gx : IMG - 1;
                    Af[j] = pa[gx]; Bf[j] = pb[gx];
                }
            }
            if (r < TOUT && cs8 < 4) {   // owned 32x32: whole item in or out
                #pragma unroll
                for (int j = 0; j < 8; ++j) {
                    const float d = Af[j] - Bf[j];
                    mse_local = fmaf(d, d, mse_local);
                }
            }
            unsigned wA[4], wB[4], wQ[4], wX[4];
            #pragma unroll
            for (int h = 0; h < 4; ++h) {
                const unsigned a0 = __float_as_uint(Af[2*h])   + 0x8000u;
                const unsigned a1 = __float_as_uint(Af[2*h+1]) + 0x8000u;
                const unsigned b0 = __float_as_uint(Bf[2*h])   + 0x8000u;
                const unsigned b1 = __float_as_uint(Bf[2*h+1]) + 0x8000u;
                const float ar0 = __uint_as_float(a0 & 0xFFFF0000u);
                const float ar1 = __uint_as_float(a1 & 0xFFFF0000u);
                const float br0 = __uint_as_float(b0 & 0xFFFF0000u);
                const float br1 = __uint_as_float(b1 & 0xFFFF0000u);
                const unsigned q0 = __float_as_uint(fmaf(ar0, ar0, br0 * br0)) + 0x8000u;
                const unsigned q1 = __float_as_uint(fmaf(ar1, ar1, br1 * br1)) + 0x8000u;
                const unsigned x0 = __float_as_uint(ar0 * br0) + 0x8000u;
                const unsigned x1 = __float_as_uint(ar1 * br1) + 0x8000u;
                wA[h] = prm(a1, a0); wB[h] = prm(b1, b0);
                wQ[h] = prm(q1, q0); wX[h] = prm(x1, x0);
            }
            if (cs8 == 5) {              // col 47 = zero pad
                wA[3] &= 0xFFFFu; wB[3] &= 0xFFFFu;
                wQ[3] &= 0xFFFFu; wX[3] &= 0xFFFFu;
            }
            uint4 vA, vB, vQ, vX;
            vA.x = wA[0]; vA.y = wA[1]; vA.z = wA[2]; vA.w = wA[3];
            vB.x = wB[0]; vB.y = wB[1]; vB.z = wB[2]; vB.w = wB[3];
            vQ.x = wQ[0]; vQ.y = wQ[1]; vQ.z = wQ[2]; vQ.w = wQ[3];
            vX.x = wX[0]; vX.y = wX[1]; vX.z = wX[2]; vX.w = wX[3];
            *(uint4*)&S[0][r][c0] = vA;
            *(uint4*)&S[1][r][c0] = vB;
            *(uint4*)&S[2][r][c0] = vQ;
            *(uint4*)&S[3][r][c0] = vX;
        }
    }
    __syncthreads();

    const int m15 = tid & 15;
    const int q4  = (tid >> 4) & 3;
    const int wid = tid >> 6;

    // banded weight fragment, identical for every wave:
    // wf[j] = g[(q4*8+j) - m15]  (zero outside band)
    bf16x8 wf;
    {
        const int base = q4 * 8 - m15 + 16;   // +j -> index into gt, in [1,47]
        #pragma unroll
        for (int j = 0; j < 8; ++j)
            wf[j] = (short)gt[base + j];
    }

    // ---------------- Phase H: horizontal conv via MFMA ----------------
    // HB[wid][oc][hr] aliases S[wid][oc][hr] (oc<32). Read the four
    // row-0..31 fragments BEFORE any write; rows 32..47 are never written.
    {
        auto hstep = [&](const bf16x8 af, const int Mt, const int Nt) {
            f32x4 c = {0.f, 0.f, 0.f, 0.f};
            c = __builtin_amdgcn_mfma_f32_16x16x32_bf16(af, wf, c, 0, 0, 0);
            // C: row = Mt*16 + q4*4 + reg, outcol = Nt*16 + m15
            const unsigned lo = prm(__float_as_uint(c[1]) + 0x8000u,
                                    __float_as_uint(c[0]) + 0x8000u);
            const unsigned hi = prm(__float_as_uint(c[3]) + 0x8000u,
                                    __float_as_uint(c[2]) + 0x8000u);
            uint2 wv; wv.x = lo; wv.y = hi;
            *(uint2*)&S[wid][Nt * 16 + m15][Mt * 16 + q4 * 4] = wv;
        };
        const bf16x8 a00 = *(const bf16x8*)&S[wid][     m15][     q4 * 8];
        const bf16x8 a01 = *(const bf16x8*)&S[wid][     m15][16 + q4 * 8];
        const bf16x8 a10 = *(const bf16x8*)&S[wid][16 + m15][     q4 * 8];
        const bf16x8 a11 = *(const bf16x8*)&S[wid][16 + m15][16 + q4 * 8];
        hstep(a00, 0, 0);   // writes rows  0..15, cols  0..15
        hstep(a01, 0, 1);   // writes rows 16..31, cols  0..15
        hstep(a10, 1, 0);   // writes rows  0..15, cols 16..31
        hstep(a11, 1, 1);   // writes rows 16..31, cols 16..31
        const bf16x8 a20 = *(const bf16x8*)&S[wid][32 + m15][     q4 * 8];
        const bf16x8 a21 = *(const bf16x8*)&S[wid][32 + m15][16 + q4 * 8];
        hstep(a20, 2, 0);   // writes rows  0..15, cols 32..47
        hstep(a21, 2, 1);   // writes rows 16..31, cols 32..47
    }
    __syncthreads();

    // ---------------- Phase V: vertical conv via MFMA + SSIM ----------------
    {
        const int Rt = wid >> 1, Ct = wid & 1;   // output quadrant
        const int ko = Rt * 16 + q4 * 8;         // hbrow K-offset
        const f32x4 z = {0.f, 0.f, 0.f, 0.f};
        const bf16x8 f0 = *(const bf16x8*)&S[0][Ct * 16 + m15][ko];
        const bf16x8 f1 = *(const bf16x8*)&S[1][Ct * 16 + m15][ko];
        const bf16x8 f2 = *(const bf16x8*)&S[2][Ct * 16 + m15][ko];
        const bf16x8 f3 = *(const bf16x8*)&S[3][Ct * 16 + m15][ko];
        const f32x4 M1 = __builtin_amdgcn_mfma_f32_16x16x32_bf16(wf, f0, z, 0, 0, 0);
        const f32x4 M2 = __builtin_amdgcn_mfma_f32_16x16x32_bf16(wf, f1, z, 0, 0, 0);
        const f32x4 Qm = __builtin_amdgcn_mfma_f32_16x16x32_bf16(wf, f2, z, 0, 0, 0);
        const f32x4 Xm = __builtin_amdgcn_mfma_f32_16x16x32_bf16(wf, f3, z, 0, 0, 0);

        const float C1u = 1.0e-4f;   // (0.01*255)^2 / 255^2
        const float C2u = 9.0e-4f;   // (0.03*255)^2 / 255^2
        const int ocol  = ox0 + Ct * 16 + m15;
        const int orow0 = oy0 + Rt * 16 + q4 * 4;
        #pragma unroll
        for (int g = 0; g < 4; ++g) {
            const float mu1  = M1[g], mu2 = M2[g];
            const float mu12 = mu1 * mu2;
            const float musq = fmaf(mu1, mu1, mu2 * mu2);
            const float sgq  = Qm[g] - musq;     // sigma1^2 + sigma2^2
            const float sg12 = Xm[g] - mu12;
            const float num  = fmaf(2.0f, mu12, C1u) * fmaf(2.0f, sg12, C2u);
            const float den  = (musq + C1u) * (sgq + C2u);
            const float val  = num * __builtin_amdgcn_rcpf(den);
            if (ocol < OUTW && (orow0 + g) < OUTW) ssim_local += val;
        }
    }

    // ---------------- Block reduction + partial write ----------------
    #pragma unroll
    for (int off = 32; off > 0; off >>= 1) {
        mse_local  += __shfl_down(mse_local,  off, 64);
        ssim_local += __shfl_down(ssim_local, off, 64);
    }
    if ((tid & 63) == 0) { red[0][wid] = mse_local; red[1][wid] = ssim_local; }
    __syncthreads();
    if (tid == 0) {
        const double m = (double)red[0][0] + (double)red[0][1]
                       + (double)red[0][2] + (double)red[0][3];
        const double s = (double)red[1][0] + (double)red[1][1]
                       + (double)red[1][2] + (double)red[1][3];
        if (TWO_STAGE) {
            const int bid = (int)blockIdx.x
                          + 16 * ((int)blockIdx.y + 16 * (int)blockIdx.z);
            partial[bid] = make_double2(m, s);
        } else {
            atomicAdd(&accum[0], m);
            atomicAdd(&accum[1], s);
        }
    }
}

// Single block, 1024 threads: 24576 partials = 1024 x 24 exactly.
__global__ __launch_bounds__(1024) void reduce_kernel(
    const double2* __restrict__ partial,
    float* __restrict__ out)
{
    __shared__ double sm[16], ss[16];
    const int tid = threadIdx.x;
    double m = 0.0, s = 0.0;
    #pragma unroll
    for (int k = 0; k < 24; ++k) {
        const double2 p = partial[tid + 1024 * k];
        m += p.x; s += p.y;
    }
    #pragma unroll
    for (int off = 32; off > 0; off >>= 1) {
        m += __shfl_down(m, off, 64);
        s += __shfl_down(s, off, 64);
    }
    if ((tid & 63) == 0) { sm[tid >> 6] = m; ss[tid >> 6] = s; }
    __syncthreads();
    if (tid == 0) {
        double M = 0.0, S = 0.0;
        #pragma unroll
        for (int w = 0; w < 16; ++w) { M += sm[w]; S += ss[w]; }
        const double mse  = M / 25165824.0;   // 32*3*512*512
        const double ssim = S / 23712864.0;   // 32*3*497*497
        out[0] = (float)(0.7 * mse + 0.3 * (1.0 - ssim));
    }
}

__global__ void finalize_kernel(const double* __restrict__ accum,
                                float* __restrict__ out)
{
    const double mse  = accum[0] / 25165824.0;
    const double ssim = accum[1] / 23712864.0;
    out[0] = (float)(0.7 * mse + 0.3 * (1.0 - ssim));
}

extern "C" void kernel_launch(void* const* d_in, const int* in_sizes, int n_in,
                              void* d_out, int out_size, void* d_ws, size_t ws_size,
                              hipStream_t stream) {
    const float* img1 = (const float*)d_in[0];
    const float* img2 = (const float*)d_in[1];
    float* out = (float*)d_out;

    // Gaussian window -> bf16 (RNE) -> packed pairs
    WinPk wpk;
    {
        double g[16], s = 0.0;
        for (int i = 0; i < 16; ++i) {
            const double c = (double)i - 7.5;
            g[i] = exp(-(c * c) / 4.5);
            s += g[i];
        }
        unsigned short h[16];
        for (int i = 0; i < 16; ++i) {
            const float gf = (float)(g[i] / s);
            unsigned u;
            memcpy(&u, &gf, 4);
            u += 0x7FFFu + ((u >> 16) & 1u);   // round-to-nearest-even
            h[i] = (unsigned short)(u >> 16);
        }
        for (int k = 0; k < 8; ++k)
            wpk.w[k] = (unsigned)h[2 * k] | ((unsigned)h[2 * k + 1] << 16);
    }

    dim3 grid(16, 16, 96);   // 16x16 tiles of 497x497, 96 = 32*3 planes
    if (ws_size >= (size_t)NBLK * sizeof(double2)) {
        double2* partial = (double2*)d_ws;
        ssim_mse_kernel<true><<<grid, dim3(256), 0, stream>>>(
            img1, img2, wpk, partial, nullptr);
        reduce_kernel<<<1, dim3(1024), 0, stream>>>(partial, out);
    } else {
        double* accum = (double*)d_ws;
        hipMemsetAsync(d_ws, 0, 2 * sizeof(double), stream);
        ssim_mse_kernel<false><<<grid, dim3(256), 0, stream>>>(
            img1, img2, wpk, nullptr, accum);
        finalize_kernel<<<1, 1, 0, stream>>>(accum, out);
    }
}

// Round 2
// 222.371 us; speedup vs baseline: 1.1049x; 1.0448x over previous
//
#include <hip/hip_runtime.h>
#include <math.h>
#include <string.h>

typedef __attribute__((ext_vector_type(8))) short bf16x8;
typedef __attribute__((ext_vector_type(4))) float f32x4;

namespace {
constexpr int IMG  = 512;
constexpr int HALO = 15;
constexpr int OUTW = IMG - HALO;    // 497
// 64x32 output tiles: grid 8 x 16 x 96
constexpr int NBLK = 8 * 16 * 96;   // 12288 blocks

// LDS geometry: 4 signal planes, each 48 rows x 80 cols staged with row
// stride 88 shorts (176 B = 11 sixteen-byte slots, ODD -> conflict-free
// b128 column access). Plane capacity 48*88 = 4224 shorts.
// H-output overlay HB[sig][oc<64][hr<48] lives in the same plane, flat at
// stride 56 shorts (112 B = 7 slots, ODD): 64*56 = 3584 <= 4224.
constexpr int SSTR = 88;            // staged row stride (shorts)
constexpr int PLN  = 48 * SSTR;     // 4224 shorts per plane
constexpr int HSTR = 56;            // HB outcol stride (shorts)

struct WinPk { unsigned w[8]; };    // 16 bf16 Gaussian weights, packed pairs

// pack two pre-rounded (+0x8000) float bit patterns into [hi.bf16 : lo.bf16]
__device__ __forceinline__ unsigned prm(unsigned hi, unsigned lo) {
    return __builtin_amdgcn_perm(hi, lo, 0x07060302u);
}
}

// One block = one 64-wide x 32-tall output tile of one (batch,channel) plane.
// MFMA formulation: 16-tap conv = GEMM vs constant banded matrix
// W[k][n] = g[k-n]. Per-lane banded fragment wf[j] = g[(q4*8+j)-m15] is the
// B-operand (horizontal pass) and A-operand (vertical pass) of
// mfma_f32_16x16x32_bf16.
//
// Phase A (480 items x 8 cols on 512 threads, single pass): stage 48x80
//   bf16 patches of 4 signals {a, b, a^2+b^2, ab} (computed FROM the
//   bf16-rounded a,b -> exact mu^2/E[x^2] consistency); row 47 / col 79
//   zero-padded (read only by zero weights; must be finite). MSE fused on
//   owned 32x64 region in fp32 (whole-item uniform test).
// Phase H: wave w -> signal s=w&3, outcol half nh=w>>2. 6 MFMA tiles
//   (3 Mtiles x 2 Ntiles): read A-fragments + MFMA + pack IN REGISTERS,
//   then barrier, then write HB (overlay of the raw plane -- the barrier
//   makes the cross-wave (2 waves/signal) aliasing race-free), barrier.
// Phase V: wave w -> output quadrant Rt=w>>2 (2 row tiles), Ct=w&3
//   (4 col tiles): per signal one MFMA (A = wf, B = HB b128), SSIM
//   rational map in fp32, masked sum.
// Tail: per-block double2 partial + reduce_kernel (or atomics fallback).
template <bool TWO_STAGE>
__global__ __launch_bounds__(512, 8)
void ssim_mse_kernel(const float* __restrict__ img1,
                     const float* __restrict__ img2,
                     WinPk wpk,
                     double2* __restrict__ partial,
                     double*  __restrict__ accum)
{
    __shared__ unsigned short S[4 * PLN];     // 33,792 B (raw planes + HB overlay)
    __shared__ unsigned short gt[64];         // banded-weight lookup
    __shared__ float red[2][8];

    const int tid = threadIdx.x;
    const int ox0 = blockIdx.x * 64;
    const int oy0 = blockIdx.y * 32;
    const size_t plane_off = (size_t)blockIdx.z * (IMG * IMG);
    const float* __restrict__ p1 = img1 + plane_off;
    const float* __restrict__ p2 = img2 + plane_off;

    float mse_local = 0.0f, ssim_local = 0.0f;

    // ---- weight table: gt[i] = bf16 g[i-16] for i in [16,32), else 0 ----
    if (tid < 16) gt[tid] = 0;
    else if (tid >= 32 && tid < 64) gt[tid] = 0;
    else if (tid == 16) {
        #pragma unroll
        for (int k = 0; k < 8; ++k)
            *(unsigned*)&gt[16 + 2 * k] = wpk.w[k];
    }

    // ---------------- Phase A: stage signals + MSE ----------------
    // 480 items = 48 rows x 10 eight-col segments; threads 480..511 idle.
    if (tid < 480) {
        const int r   = (int)((unsigned)tid / 10u);
        const int cs8 = tid - 10 * r;
        const int c0  = 8 * cs8;
        const int sb  = r * SSTR + c0;        // short offset within plane
        if (r == 47) {                        // zero pad row
            const uint4 z = make_uint4(0u, 0u, 0u, 0u);
            *(uint4*)&S[0 * PLN + sb] = z;
            *(uint4*)&S[1 * PLN + sb] = z;
            *(uint4*)&S[2 * PLN + sb] = z;
            *(uint4*)&S[3 * PLN + sb] = z;
        } else {
            const int gy  = oy0 + r;
            const int gyc = gy < IMG ? gy : IMG - 1;
            const float* __restrict__ pa = p1 + (size_t)gyc * IMG;
            const float* __restrict__ pb = p2 + (size_t)gyc * IMG;
            float Af[8], Bf[8];
            if (ox0 + c0 + 8 <= IMG) {
                const float4 va0 = *(const float4*)(pa + ox0 + c0);
                const float4 va1 = *(const float4*)(pa + ox0 + c0 + 4);
                const float4 vb0 = *(const float4*)(pb + ox0 + c0);
                const float4 vb1 = *(const float4*)(pb + ox0 + c0 + 4);
                Af[0] = va0.x; Af[1] = va0.y; Af[2] = va0.z; Af[3] = va0.w;
                Af[4] = va1.x; Af[5] = va1.y; Af[6] = va1.z; Af[7] = va1.w;
                Bf[0] = vb0.x; Bf[1] = vb0.y; Bf[2] = vb0.z; Bf[3] = vb0.w;
                Bf[4] = vb1.x; Bf[5] = vb1.y; Bf[6] = vb1.z; Bf[7] = vb1.w;
            } else {
                #pragma unroll
                for (int j = 0; j < 8; ++j) {
                    int gx = ox0 + c0 + j; gx = gx < IMG ? gx : IMG - 1;
                    Af[j] = pa[gx]; Bf[j] = pb[gx];
                }
            }
            if (r < 32 && cs8 < 8) {   // owned 32x64: whole item in or out
                #pragma unroll
                for (int j = 0; j < 8; ++j) {
                    const float d = Af[j] - Bf[j];
                    mse_local = fmaf(d, d, mse_local);
                }
            }
            unsigned wA[4], wB[4], wQ[4], wX[4];
            #pragma unroll
            for (int h = 0; h < 4; ++h) {
                const unsigned a0 = __float_as_uint(Af[2*h])   + 0x8000u;
                const unsigned a1 = __float_as_uint(Af[2*h+1]) + 0x8000u;
                const unsigned b0 = __float_as_uint(Bf[2*h])   + 0x8000u;
                const unsigned b1 = __float_as_uint(Bf[2*h+1]) + 0x8000u;
                const float ar0 = __uint_as_float(a0 & 0xFFFF0000u);
                const float ar1 = __uint_as_float(a1 & 0xFFFF0000u);
                const float br0 = __uint_as_float(b0 & 0xFFFF0000u);
                const float br1 = __uint_as_float(b1 & 0xFFFF0000u);
                const unsigned q0 = __float_as_uint(fmaf(ar0, ar0, br0 * br0)) + 0x8000u;
                const unsigned q1 = __float_as_uint(fmaf(ar1, ar1, br1 * br1)) + 0x8000u;
                const unsigned x0 = __float_as_uint(ar0 * br0) + 0x8000u;
                const unsigned x1 = __float_as_uint(ar1 * br1) + 0x8000u;
                wA[h] = prm(a1, a0); wB[h] = prm(b1, b0);
                wQ[h] = prm(q1, q0); wX[h] = prm(x1, x0);
            }
            if (cs8 == 9) {              // col 79 = zero pad
                wA[3] &= 0xFFFFu; wB[3] &= 0xFFFFu;
                wQ[3] &= 0xFFFFu; wX[3] &= 0xFFFFu;
            }
            uint4 vA, vB, vQ, vX;
            vA.x = wA[0]; vA.y = wA[1]; vA.z = wA[2]; vA.w = wA[3];
            vB.x = wB[0]; vB.y = wB[1]; vB.z = wB[2]; vB.w = wB[3];
            vQ.x = wQ[0]; vQ.y = wQ[1]; vQ.z = wQ[2]; vQ.w = wQ[3];
            vX.x = wX[0]; vX.y = wX[1]; vX.z = wX[2]; vX.w = wX[3];
            *(uint4*)&S[0 * PLN + sb] = vA;
            *(uint4*)&S[1 * PLN + sb] = vB;
            *(uint4*)&S[2 * PLN + sb] = vQ;
            *(uint4*)&S[3 * PLN + sb] = vX;
        }
    }
    __syncthreads();

    const int m15 = tid & 15;
    const int q4  = (tid >> 4) & 3;
    const int wid = tid >> 6;

    // banded weight fragment, identical for every wave:
    // wf[j] = g[(q4*8+j) - m15]  (zero outside band)
    bf16x8 wf;
    {
        const int base = q4 * 8 - m15 + 16;   // +j -> index into gt, in [1,47]
        #pragma unroll
        for (int j = 0; j < 8; ++j)
            wf[j] = (short)gt[base + j];
    }

    // ---------------- Phase H: horizontal conv via MFMA ----------------
    // wave w: signal s = w&3, outcol half nh = w>>2 (Nt = 2*nh + NtL).
    // Read all 6 A-fragments + MFMA + pack BEFORE barrier; write HB after.
    {
        const int s  = wid & 3;
        const int nh = wid >> 2;
        uint2 hw[6];
        #pragma unroll
        for (int NtL = 0; NtL < 2; ++NtL) {
            const int Nt = 2 * nh + NtL;
            #pragma unroll
            for (int Mt = 0; Mt < 3; ++Mt) {
                const bf16x8 af = *(const bf16x8*)
                    &S[s * PLN + (Mt * 16 + m15) * SSTR + Nt * 16 + q4 * 8];
                f32x4 c = {0.f, 0.f, 0.f, 0.f};
                c = __builtin_amdgcn_mfma_f32_16x16x32_bf16(af, wf, c, 0, 0, 0);
                // C: row = Mt*16 + q4*4 + reg, outcol = Nt*16 + m15
                const unsigned lo = prm(__float_as_uint(c[1]) + 0x8000u,
                                        __float_as_uint(c[0]) + 0x8000u);
                const unsigned hi = prm(__float_as_uint(c[3]) + 0x8000u,
                                        __float_as_uint(c[2]) + 0x8000u);
                uint2 wv; wv.x = lo; wv.y = hi;
                hw[NtL * 3 + Mt] = wv;
            }
        }
        __syncthreads();   // all raw-plane reads complete before HB overlay
        #pragma unroll
        for (int NtL = 0; NtL < 2; ++NtL) {
            const int Nt = 2 * nh + NtL;
            #pragma unroll
            for (int Mt = 0; Mt < 3; ++Mt) {
                const int oc = Nt * 16 + m15;
                const int hr = Mt * 16 + q4 * 4;
                *(uint2*)&S[s * PLN + oc * HSTR + hr] = hw[NtL * 3 + Mt];
            }
        }
    }
    __syncthreads();

    // ---------------- Phase V: vertical conv via MFMA + SSIM ----------------
    {
        const int Rt = wid >> 2, Ct = wid & 3;   // output quadrant (2x4)
        const int ko = Rt * 16 + q4 * 8;         // hbrow K-offset
        const int ob = (Ct * 16 + m15) * HSTR + ko;
        const f32x4 z = {0.f, 0.f, 0.f, 0.f};
        const bf16x8 f0 = *(const bf16x8*)&S[0 * PLN + ob];
        const bf16x8 f1 = *(const bf16x8*)&S[1 * PLN + ob];
        const bf16x8 f2 = *(const bf16x8*)&S[2 * PLN + ob];
        const bf16x8 f3 = *(const bf16x8*)&S[3 * PLN + ob];
        const f32x4 M1 = __builtin_amdgcn_mfma_f32_16x16x32_bf16(wf, f0, z, 0, 0, 0);
        const f32x4 M2 = __builtin_amdgcn_mfma_f32_16x16x32_bf16(wf, f1, z, 0, 0, 0);
        const f32x4 Qm = __builtin_amdgcn_mfma_f32_16x16x32_bf16(wf, f2, z, 0, 0, 0);
        const f32x4 Xm = __builtin_amdgcn_mfma_f32_16x16x32_bf16(wf, f3, z, 0, 0, 0);

        const float C1u = 1.0e-4f;   // (0.01*255)^2 / 255^2
        const float C2u = 9.0e-4f;   // (0.03*255)^2 / 255^2
        const int ocol  = ox0 + Ct * 16 + m15;
        const int orow0 = oy0 + Rt * 16 + q4 * 4;
        #pragma unroll
        for (int g = 0; g < 4; ++g) {
            const float mu1  = M1[g], mu2 = M2[g];
            const float mu12 = mu1 * mu2;
            const float musq = fmaf(mu1, mu1, mu2 * mu2);
            const float sgq  = Qm[g] - musq;     // sigma1^2 + sigma2^2
            const float sg12 = Xm[g] - mu12;
            const float num  = fmaf(2.0f, mu12, C1u) * fmaf(2.0f, sg12, C2u);
            const float den  = (musq + C1u) * (sgq + C2u);
            const float val  = num * __builtin_amdgcn_rcpf(den);
            if (ocol < OUTW && (orow0 + g) < OUTW) ssim_local += val;
        }
    }

    // ---------------- Block reduction + partial write ----------------
    #pragma unroll
    for (int off = 32; off > 0; off >>= 1) {
        mse_local  += __shfl_down(mse_local,  off, 64);
        ssim_local += __shfl_down(ssim_local, off, 64);
    }
    if ((tid & 63) == 0) { red[0][wid] = mse_local; red[1][wid] = ssim_local; }
    __syncthreads();
    if (tid == 0) {
        double m = 0.0, s = 0.0;
        #pragma unroll
        for (int w = 0; w < 8; ++w) {
            m += (double)red[0][w];
            s += (double)red[1][w];
        }
        if (TWO_STAGE) {
            const int bid = (int)blockIdx.x
                          + 8 * ((int)blockIdx.y + 16 * (int)blockIdx.z);
            partial[bid] = make_double2(m, s);
        } else {
            atomicAdd(&accum[0], m);
            atomicAdd(&accum[1], s);
        }
    }
}

// Single block, 1024 threads: 12288 partials = 1024 x 12 exactly.
__global__ __launch_bounds__(1024) void reduce_kernel(
    const double2* __restrict__ partial,
    float* __restrict__ out)
{
    __shared__ double sm[16], ss[16];
    const int tid = threadIdx.x;
    double m = 0.0, s = 0.0;
    #pragma unroll
    for (int k = 0; k < 12; ++k) {
        const double2 p = partial[tid + 1024 * k];
        m += p.x; s += p.y;
    }
    #pragma unroll
    for (int off = 32; off > 0; off >>= 1) {
        m += __shfl_down(m, off, 64);
        s += __shfl_down(s, off, 64);
    }
    if ((tid & 63) == 0) { sm[tid >> 6] = m; ss[tid >> 6] = s; }
    __syncthreads();
    if (tid == 0) {
        double M = 0.0, S = 0.0;
        #pragma unroll
        for (int w = 0; w < 16; ++w) { M += sm[w]; S += ss[w]; }
        const double mse  = M / 25165824.0;   // 32*3*512*512
        const double ssim = S / 23712864.0;   // 32*3*497*497
        out[0] = (float)(0.7 * mse + 0.3 * (1.0 - ssim));
    }
}

__global__ void finalize_kernel(const double* __restrict__ accum,
                                float* __restrict__ out)
{
    const double mse  = accum[0] / 25165824.0;
    const double ssim = accum[1] / 23712864.0;
    out[0] = (float)(0.7 * mse + 0.3 * (1.0 - ssim));
}

extern "C" void kernel_launch(void* const* d_in, const int* in_sizes, int n_in,
                              void* d_out, int out_size, void* d_ws, size_t ws_size,
                              hipStream_t stream) {
    const float* img1 = (const float*)d_in[0];
    const float* img2 = (const float*)d_in[1];
    float* out = (float*)d_out;

    // Gaussian window -> bf16 (RNE) -> packed pairs
    WinPk wpk;
    {
        double g[16], s = 0.0;
        for (int i = 0; i < 16; ++i) {
            const double c = (double)i - 7.5;
            g[i] = exp(-(c * c) / 4.5);
            s += g[i];
        }
        unsigned short h[16];
        for (int i = 0; i < 16; ++i) {
            const float gf = (float)(g[i] / s);
            unsigned u;
            memcpy(&u, &gf, 4);
            u += 0x7FFFu + ((u >> 16) & 1u);   // round-to-nearest-even
            h[i] = (unsigned short)(u >> 16);
        }
        for (int k = 0; k < 8; ++k)
            wpk.w[k] = (unsigned)h[2 * k] | ((unsigned)h[2 * k + 1] << 16);
    }

    dim3 grid(8, 16, 96);   // 8x16 tiles (64x32) of 497x497, 96 = 32*3 planes
    if (ws_size >= (size_t)NBLK * sizeof(double2)) {
        double2* partial = (double2*)d_ws;
        ssim_mse_kernel<true><<<grid, dim3(512), 0, stream>>>(
            img1, img2, wpk, partial, nullptr);
        reduce_kernel<<<1, dim3(1024), 0, stream>>>(partial, out);
    } else {
        double* accum = (double*)d_ws;
        hipMemsetAsync(d_ws, 0, 2 * sizeof(double), stream);
        ssim_mse_kernel<false><<<grid, dim3(512), 0, stream>>>(
            img1, img2, wpk, nullptr, accum);
        finalize_kernel<<<1, 1, 0, stream>>>(accum, out);
    }
}